// Round 12
// baseline (12514.716 us; speedup 1.0000x reference)
//
#include <hip/hip_runtime.h>

// ---------------- problem dims ----------------
constexpr int BB = 16;       // batch
constexpr int TT = 256;      // seq len
constexpr int IN0 = 512;     // input dim (layer 0)
constexpr int HH = 1024;     // hidden
constexpr int GG = 4096;     // 4*H gates
constexpr int NLAYERS = 8;
constexpr int NWG = 128;     // scan workgroups (512 thr each)

// ---------------- ws layout (bytes) ----------------
constexpr size_t XG_OFF   = 0;                         // xg2 [t*16+b][4096] fp32 : 64 MB
constexpr size_t REG0_OFF = 67108864;                  // 16 MB region 0 (Wcv / hs even layers)
constexpr size_t REG1_OFF = REG0_OFF + 16777216;       // 16 MB region 1 (Xcv0 / Wcv / hs odd)
constexpr size_t HG2_OFF  = REG1_OFF + 16777216;       // h parity packed: 2 x 16384 u32 = 128 KB
constexpr size_t FC1_OFF  = HG2_OFF + 131072;
constexpr size_t FC2_OFF  = FC1_OFF + 32768;
constexpr size_t BAR_OFF  = FC2_OFF + 16384;           // barrier state (4 KB)
// bar (unsigned): arrive counter @ 0 (monotonic, never reset);
//                 gen copy[g] @ 512+g*16 (8 lines, 16 pollers each)

// ---------------- scan LDS ----------------
// partials: [8 waves][2 tiles][16 rows pad 17] = 8*544 floats
constexpr int SMEM_BYTES = 90112;  // pad >80K: force 1 WG/CU

typedef __attribute__((ext_vector_type(8))) short bf16x8;
typedef __attribute__((ext_vector_type(4))) float f32x4;

__device__ __forceinline__ unsigned short f2bf(float f)
{
    union { float f; unsigned u; } v{f};
    unsigned r = v.u + 0x7FFFu + ((v.u >> 16) & 1u);   // RNE
    return (unsigned short)(r >> 16);
}
__device__ __forceinline__ float bf2f(unsigned short h)
{
    union { unsigned u; float f; } v{(unsigned)h << 16};
    return v.f;
}

// ---------------- split conversion: fp32 -> bf16 hi + bf16 lo ----------------
__global__ __launch_bounds__(256) void conv_split(const float* __restrict__ in,
                                                  ushort* __restrict__ oh,
                                                  ushort* __restrict__ ol, int n4)
{
    int g = blockIdx.x * blockDim.x + threadIdx.x;
    if (g >= n4) return;
    float4 f = ((const float4*)in)[g];
    ushort4 h, l;
    h.x = f2bf(f.x); l.x = f2bf(f.x - bf2f(h.x));
    h.y = f2bf(f.y); l.y = f2bf(f.y - bf2f(h.y));
    h.z = f2bf(f.z); l.z = f2bf(f.z - bf2f(h.z));
    h.w = f2bf(f.w); l.w = f2bf(f.w - bf2f(h.w));
    ((ushort4*)oh)[g] = h;
    ((ushort4*)ol)[g] = l;
}

// ---------------- MFMA GEMM (unchanged, verified) ----------------
__global__ __launch_bounds__(256) void gemm_mfma(const ushort* __restrict__ Ah,
                                                 const ushort* __restrict__ Al,
                                                 const ushort* __restrict__ Wh,
                                                 const ushort* __restrict__ Wl,
                                                 const float* __restrict__ bih,
                                                 const float* __restrict__ bhh,
                                                 float* __restrict__ out, int K)
{
    __shared__ ushort lds[2][128 * 72];
    const int tid = threadIdx.x;
    const int w = tid >> 6, ln = tid & 63;
    const int m0 = blockIdx.y * 128, n0 = blockIdx.x * 128;
    const int arow = (w >> 1) * 64, bcol = (w & 1) * 64;
    const int lm = ln & 15, lk = (ln >> 4) * 8;
    const int sr = tid >> 3, sc = (tid & 7) * 8;

    f32x4 acc[4][4] = {};

#pragma unroll
    for (int s = 0; s < 3; ++s) {
        const ushort* Asrc = (s < 2) ? Ah : Al;
        const ushort* Bsrc = (s == 1) ? Wl : Wh;
        for (int k0 = 0; k0 < K; k0 += 64) {
            __syncthreads();
#pragma unroll
            for (int i = 0; i < 4; ++i) {
                int r = sr + 32 * i;
                *(uint4*)&lds[0][r * 72 + sc] =
                    *(const uint4*)(Asrc + (size_t)(m0 + r) * K + k0 + sc);
                *(uint4*)&lds[1][r * 72 + sc] =
                    *(const uint4*)(Bsrc + (size_t)(n0 + r) * K + k0 + sc);
            }
            __syncthreads();
#pragma unroll
            for (int ks = 0; ks < 2; ++ks) {
                bf16x8 af[4], bf[4];
#pragma unroll
                for (int i = 0; i < 4; ++i)
                    af[i] = *(const bf16x8*)&lds[0][(arow + i * 16 + lm) * 72 + ks * 32 + lk];
#pragma unroll
                for (int j = 0; j < 4; ++j)
                    bf[j] = *(const bf16x8*)&lds[1][(bcol + j * 16 + lm) * 72 + ks * 32 + lk];
#pragma unroll
                for (int i = 0; i < 4; ++i)
#pragma unroll
                    for (int j = 0; j < 4; ++j)
                        acc[i][j] = __builtin_amdgcn_mfma_f32_16x16x32_bf16(
                            af[i], bf[j], acc[i][j], 0, 0, 0);
            }
        }
    }

#pragma unroll
    for (int j = 0; j < 4; ++j) {
        const int n = n0 + bcol + j * 16 + lm;
        const float bsum = bih[n] + bhh[n];
#pragma unroll
        for (int i = 0; i < 4; ++i) {
            const int mrow = m0 + arow + i * 16 + (ln >> 4) * 4;
#pragma unroll
            for (int r = 0; r < 4; ++r) {
                const int m = mrow + r;
                const int bb = m >> 8, tt = m & 255;
                out[(size_t)(tt * 16 + bb) * GG + n] = acc[i][j][r] + bsum;
            }
        }
    }
}

__device__ __forceinline__ float sigf(float x) { return 1.0f / (1.0f + expf(-x)); }

// ---------------- per-layer LSTM scan: direct-global B-frags, flat barrier -----------
// 128 WG x 512 thr. WG wg owns h-cols j0=8wg..8wg+7 -> 32 gate rows r: gate=r>>3,
// col=j0+(r&7). Wave w owns k-slice [128w,128w+128) for BOTH 16-row tiles
// (tile T rows T*16..T*16+15). Lane ln: kq=ln>>4, m=ln&15 (tile row / batch).
// h exchanged packed (bf16 hi | lo<<16) via parity buffers, loaded per-wave
// directly into B fragments (each u32 read once per WG).
__global__ __launch_bounds__(512, 1) void lstm_scan(const float* __restrict__ Whh,
                                                    const float* __restrict__ xg,
                                                    ushort* __restrict__ hseq_hi,
                                                    ushort* __restrict__ hseq_lo,
                                                    unsigned* __restrict__ hglob2p,
                                                    unsigned* __restrict__ bar,
                                                    unsigned lbase)
{
    extern __shared__ float smem[];

    const int tid = threadIdx.x;
    const int wg  = blockIdx.x;
    const int j0  = wg << 3;
    const int w   = tid >> 6;
    const int ln  = tid & 63;
    const int m   = ln & 15;
    const int kq  = ln >> 4;

    // ---- preload W fragments (step-invariant): [tile][4 ksteps] x (hi,lo)
    bf16x8 wf_hi[2][4], wf_lo[2][4];
#pragma unroll
    for (int T = 0; T < 2; ++T) {
        const int r = T * 16 + m;
        const int grow = ((r >> 3) << 10) + j0 + (r & 7);
        const float* wrow = Whh + (size_t)grow * 1024 + (w << 7) + (kq << 3);
#pragma unroll
        for (int s = 0; s < 4; ++s) {
            float4 f0 = *(const float4*)(wrow + s * 32);
            float4 f1 = *(const float4*)(wrow + s * 32 + 4);
            float fv[8] = {f0.x, f0.y, f0.z, f0.w, f1.x, f1.y, f1.z, f1.w};
            bf16x8 h8, l8;
#pragma unroll
            for (int i = 0; i < 8; ++i) {
                unsigned short hb = f2bf(fv[i]);
                float rr = fv[i] - bf2f(hb);
                h8[i] = (short)hb;
                l8[i] = (short)f2bf(rr);
            }
            wf_hi[T][s] = h8;
            wf_lo[T][s] = l8;
        }
    }

    // gate lanes (tid<64): q = col-pair 0..3, bg = batch
    const int q = tid >> 4, bg = tid & 15;

    unsigned* genc = bar + 512 + ((wg >> 4) << 4);

    float cs0 = 0.0f, cs1 = 0.0f;

    // xg prefetch for t=0 (gate lanes only): float2 per gate, cols (j0+2q, j0+2q+1)
    float2 xgp[4] = {};
    if (tid < 64) {
#pragma unroll
        for (int g = 0; g < 4; ++g)
            xgp[g] = *(const float2*)(xg + (size_t)(0 * 16 + bg) * GG + g * 1024 + j0 + 2 * q);
    }

    for (int t = 0; t < TT; ++t) {
        // ---- 1. detect h(t-1) published (tid0 poll, relaxed, spread gen lines)
        if (t > 0 && tid == 0) {
            const unsigned tgt = lbase + (unsigned)t;
            while (__hip_atomic_load(genc, __ATOMIC_RELAXED, __HIP_MEMORY_SCOPE_AGENT) < tgt)
                __builtin_amdgcn_s_sleep(1);
        }
        __syncthreads();

        f32x4 asum0 = {0.f, 0.f, 0.f, 0.f};
        f32x4 asum1 = {0.f, 0.f, 0.f, 0.f};
        if (t > 0) {
            // ---- 2. load packed h(t-1) B-frags direct from parity buffer
            const unsigned* hb = hglob2p + (((t - 1) & 1) << 14);
            uint4 hv[4][2];
#pragma unroll
            for (int s = 0; s < 4; ++s) {
                const int k0 = (w << 7) + (s << 5) + (kq << 3);
                const unsigned* p = hb + ((k0 >> 6) << 10) + (m << 6) + (k0 & 63);
                asm volatile("global_load_dwordx4 %0, %2, off sc0 sc1\n\t"
                             "global_load_dwordx4 %1, %2, off offset:16 sc0 sc1"
                             : "=&v"(hv[s][0]), "=&v"(hv[s][1])
                             : "v"(p) : "memory");
            }
            asm volatile("s_waitcnt vmcnt(0)" ::: "memory");
            __builtin_amdgcn_sched_barrier(0);

            // ---- 3. unpack + 24 MFMAs (6 independent chains)
            f32x4 aA0 = {0.f,0.f,0.f,0.f}, aB0 = {0.f,0.f,0.f,0.f}, aC0 = {0.f,0.f,0.f,0.f};
            f32x4 aA1 = {0.f,0.f,0.f,0.f}, aB1 = {0.f,0.f,0.f,0.f}, aC1 = {0.f,0.f,0.f,0.f};
#pragma unroll
            for (int s = 0; s < 4; ++s) {
                unsigned ua[8] = {hv[s][0].x, hv[s][0].y, hv[s][0].z, hv[s][0].w,
                                  hv[s][1].x, hv[s][1].y, hv[s][1].z, hv[s][1].w};
                bf16x8 bh, bl;
#pragma unroll
                for (int i = 0; i < 8; ++i) {
                    bh[i] = (short)(ua[i] & 0xFFFFu);
                    bl[i] = (short)(ua[i] >> 16);
                }
                aA0 = __builtin_amdgcn_mfma_f32_16x16x32_bf16(wf_hi[0][s], bh, aA0, 0, 0, 0);
                aA1 = __builtin_amdgcn_mfma_f32_16x16x32_bf16(wf_hi[1][s], bh, aA1, 0, 0, 0);
                aB0 = __builtin_amdgcn_mfma_f32_16x16x32_bf16(wf_hi[0][s], bl, aB0, 0, 0, 0);
                aB1 = __builtin_amdgcn_mfma_f32_16x16x32_bf16(wf_hi[1][s], bl, aB1, 0, 0, 0);
                aC0 = __builtin_amdgcn_mfma_f32_16x16x32_bf16(wf_lo[0][s], bh, aC0, 0, 0, 0);
                aC1 = __builtin_amdgcn_mfma_f32_16x16x32_bf16(wf_lo[1][s], bh, aC1, 0, 0, 0);
            }
            asum0 = aA0 + aB0;  asum0 = asum0 + aC0;
            asum1 = aA1 + aB1;  asum1 = asum1 + aC1;
        }

        // ---- 4. partials: [wave][tile][row=kq*4+r pad17][b=m]
#pragma unroll
        for (int r = 0; r < 4; ++r) {
            smem[w * 544 +       ((kq << 2) + r) * 17 + m] = asum0[r];
            smem[w * 544 + 272 + ((kq << 2) + r) * 17 + m] = asum1[r];
        }
        __syncthreads();

        // ---- 5. gates (wave 0): reduce 8 wave-partials + xg, activations, h store
        unsigned pk0 = 0, pk1 = 0;
        if (tid < 64) {
#pragma unroll
            for (int cc = 0; cc < 2; ++cc) {
                const int ch = 2 * q + cc;
                float iv = cc ? xgp[0].y : xgp[0].x;
                float fv = cc ? xgp[1].y : xgp[1].x;
                float gv = cc ? xgp[2].y : xgp[2].x;
                float ov = cc ? xgp[3].y : xgp[3].x;
#pragma unroll
                for (int s = 0; s < 8; ++s) {
                    iv += smem[s * 544 +       (ch    ) * 17 + bg];
                    fv += smem[s * 544 +       (ch + 8) * 17 + bg];
                    gv += smem[s * 544 + 272 + (ch    ) * 17 + bg];
                    ov += smem[s * 544 + 272 + (ch + 8) * 17 + bg];
                }
                float& cs = cc ? cs1 : cs0;
                cs = sigf(fv) * cs + sigf(iv) * tanhf(gv);
                float hval = sigf(ov) * tanhf(cs);
                unsigned short hh_ = f2bf(hval);
                unsigned short hl_ = f2bf(hval - bf2f(hh_));
                unsigned pk = (unsigned)hh_ | ((unsigned)hl_ << 16);
                if (cc) pk1 = pk; else pk0 = pk;
                const int col = j0 + ch;
                unsigned* hdst = hglob2p + ((t & 1) << 14) +
                                 ((col >> 6) << 10) + (bg << 6) + (col & 63);
                asm volatile("global_store_dword %0, %1, off sc0 sc1"
                             :: "v"(hdst), "v"(pk) : "memory");
            }
        }

        // ---- 6. arrive (monotonic single line); last arriver publishes gen
        if (tid == 0) {
            asm volatile("s_waitcnt vmcnt(0)" ::: "memory");   // wave-0 h stores acked
            unsigned a = __hip_atomic_fetch_add(bar, 1u, __ATOMIC_RELAXED,
                                                __HIP_MEMORY_SCOPE_AGENT);
            const unsigned done = 128u * (lbase + (unsigned)t + 1u);
            if (a == done - 1u) {
                const unsigned gv_ = lbase + (unsigned)t + 1u;
#pragma unroll
                for (int i = 0; i < 8; ++i)
                    __hip_atomic_store(bar + 512 + (i << 4), gv_,
                                       __ATOMIC_RELAXED, __HIP_MEMORY_SCOPE_AGENT);
            }
        }

        // ---- 7. off critical path: hseq + next-step xg prefetch
        if (tid < 64) {
#pragma unroll
            for (int cc = 0; cc < 2; ++cc) {
                const int col = j0 + 2 * q + cc;
                const unsigned pk = cc ? pk1 : pk0;
                size_t idx = (size_t)(bg * TT + t) * HH + col;
                hseq_hi[idx] = (ushort)(pk & 0xFFFFu);
                hseq_lo[idx] = (ushort)(pk >> 16);
            }
            if (t + 1 < TT) {
#pragma unroll
                for (int g = 0; g < 4; ++g)
                    xgp[g] = *(const float2*)(xg + (size_t)((t + 1) * 16 + bg) * GG +
                                              g * 1024 + j0 + 2 * q);
            }
        }
    }
}

// ---------------- FC head ----------------
__global__ void fc_relu_split(const ushort* __restrict__ ih, const ushort* __restrict__ il,
                              const float* __restrict__ w, const float* __restrict__ b,
                              float* __restrict__ out, int N, int K)
{
    int g = blockIdx.x * blockDim.x + threadIdx.x;
    if (g >= BB * N) return;
    int bi = g / N, n = g - bi * N;
    const ushort* ph = ih + (size_t)(bi * 256 + 255) * 1024;
    const ushort* pl = il + (size_t)(bi * 256 + 255) * 1024;
    const float* wp = w + (size_t)n * K;
    float s = 0.f;
    for (int k = 0; k < K; k += 4) {
        ushort4 uh = *(const ushort4*)(ph + k);
        ushort4 ul = *(const ushort4*)(pl + k);
        float4 qv = *(const float4*)(wp + k);
        s += (bf2f(uh.x) + bf2f(ul.x)) * qv.x + (bf2f(uh.y) + bf2f(ul.y)) * qv.y +
             (bf2f(uh.z) + bf2f(ul.z)) * qv.z + (bf2f(uh.w) + bf2f(ul.w)) * qv.w;
    }
    s += b[n];
    out[g] = fmaxf(s, 0.f);
}

__global__ void fc_relu(const float* __restrict__ in, const float* __restrict__ w,
                        const float* __restrict__ b, float* __restrict__ out,
                        int N, int K, int do_relu)
{
    int g = blockIdx.x * blockDim.x + threadIdx.x;
    if (g >= BB * N) return;
    int bi = g / N, n = g - bi * N;
    const float* ip = in + (size_t)bi * K;
    const float* wp = w + (size_t)n * K;
    float s = 0.f;
    for (int k = 0; k < K; k += 4) {
        float4 a = *(const float4*)(ip + k);
        float4 qv = *(const float4*)(wp + k);
        s += a.x * qv.x + a.y * qv.y + a.z * qv.z + a.w * qv.w;
    }
    s += b[n];
    if (do_relu) s = fmaxf(s, 0.f);
    out[g] = s;
}

// ---------------- launch ----------------
extern "C" void kernel_launch(void* const* d_in, const int* in_sizes, int n_in,
                              void* d_out, int out_size, void* d_ws, size_t ws_size,
                              hipStream_t stream)
{
    const float* x    = (const float*)d_in[0];
    const float* Wih0 = (const float*)d_in[1];
    const float* WihR = (const float*)d_in[2];
    const float* Whh  = (const float*)d_in[3];
    const float* bih  = (const float*)d_in[4];
    const float* bhh  = (const float*)d_in[5];
    const float* fc1w = (const float*)d_in[6];
    const float* fc1b = (const float*)d_in[7];
    const float* fc2w = (const float*)d_in[8];
    const float* fc2b = (const float*)d_in[9];
    const float* fc3w = (const float*)d_in[10];
    const float* fc3b = (const float*)d_in[11];
    float* out = (float*)d_out;
    char* ws = (char*)d_ws;

    float* xg       = (float*)(ws + XG_OFF);
    ushort* reg_[2] = {(ushort*)(ws + REG0_OFF), (ushort*)(ws + REG1_OFF)};
    unsigned* hglob2p = (unsigned*)(ws + HG2_OFF);
    float* fc1o     = (float*)(ws + FC1_OFF);
    float* fc2o     = (float*)(ws + FC2_OFF);
    unsigned* bar   = (unsigned*)(ws + BAR_OFF);

    (void)hipFuncSetAttribute((const void*)lstm_scan,
                              hipFuncAttributeMaxDynamicSharedMemorySize, SMEM_BYTES);
    (void)hipMemsetAsync(ws + BAR_OFF, 0, 4096, stream);   // arrive + gen = 0 (monotonic)

    // layer-0 X conversion into region 1 (dead before Wcv(1) is written)
    ushort* xcv_hi = reg_[1];
    ushort* xcv_lo = reg_[1] + 2097152;
    conv_split<<<2048, 256, 0, stream>>>(x, xcv_hi, xcv_lo, (BB * TT * IN0) / 4);

    for (int l = 0; l < NLAYERS; ++l) {
        const int K = (l == 0) ? IN0 : HH;
        const float* Wl_f = (l == 0) ? Wih0 : (WihR + (size_t)(l - 1) * GG * HH);

        ushort* wh = reg_[l & 1];
        ushort* wl = wh + 4194304;
        const int n4 = GG * K / 4;
        conv_split<<<(n4 + 255) / 256, 256, 0, stream>>>(Wl_f, wh, wl, n4);

        const ushort* ah = (l == 0) ? xcv_hi : reg_[(l - 1) & 1];
        const ushort* al = (l == 0) ? xcv_lo : (reg_[(l - 1) & 1] + 4194304);

        gemm_mfma<<<dim3(32, 32), 256, 0, stream>>>(
            ah, al, wh, wl, bih + (size_t)l * GG, bhh + (size_t)l * GG, xg, K);

        ushort* hs_hi = reg_[l & 1];
        ushort* hs_lo = reg_[l & 1] + 4194304;
        const float* whh_l = Whh + (size_t)l * GG * HH;
        unsigned lbase = (unsigned)(TT * l);
        void* args[7] = {(void*)&whh_l, (void*)&xg, (void*)&hs_hi, (void*)&hs_lo,
                         (void*)&hglob2p, (void*)&bar, (void*)&lbase};
        hipError_t e = hipLaunchCooperativeKernel((void*)lstm_scan, dim3(NWG), dim3(512),
                                                  args, SMEM_BYTES, stream);
        if (e != hipSuccess) {
            lstm_scan<<<dim3(NWG), dim3(512), SMEM_BYTES, stream>>>(
                whh_l, xg, hs_hi, hs_lo, hglob2p, bar, lbase);
        }
    }

    // FC head: hs(7) is in region 1
    fc_relu_split<<<32, 256, 0, stream>>>(reg_[1], reg_[1] + 4194304,
                                          fc1w, fc1b, fc1o, 512, 1024);
    fc_relu<<<16, 256, 0, stream>>>(fc1o, fc2w, fc2b, fc2o, 256, 512, 1);
    fc_relu<<<1, 16, 0, stream>>>(fc2o, fc3w, fc3b, out, 1, 256, 0);
}

// Round 13
// 7387.088 us; speedup vs baseline: 1.6941x; 1.6941x over previous
//
#include <hip/hip_runtime.h>

// ---------------- problem dims ----------------
constexpr int BB = 16;       // batch
constexpr int TT = 256;      // seq len
constexpr int IN0 = 512;     // input dim (layer 0)
constexpr int HH = 1024;     // hidden
constexpr int GG = 4096;     // 4*H gates
constexpr int NLAYERS = 8;

// ---------------- ws layout (bytes) ----------------
constexpr size_t XG_OFF   = 0;                         // xg [t*16+b][4096] fp32 : 64 MB
constexpr size_t REG0_OFF = 67108864;                  // 16 MB: W_ih splits (xcv+W0 in phase 0)
constexpr size_t REG1_OFF = REG0_OFF + 16777216;       // 16 MB: hseq hi/lo (odd layers out)
constexpr size_t HE_OFF   = REG1_OFF + 16777216;       // even-layer h: 4 slots x 64 KB
constexpr size_t HO_OFF   = HE_OFF + 262144;           // odd-layer h: 4 slots x 64 KB
constexpr size_t FC1_OFF  = HO_OFF + 262144;           // 32 KB
constexpr size_t FC2_OFF  = FC1_OFF + 32768;           // 16 KB
constexpr size_t BAR_OFF  = FC2_OFF + 16384;           // barE @ +0, barO @ +4096
// bar layout (u32 idx): arrive[g] @ g*16 (g<8, monotonic); root @ 256 (monotonic);
//                       gen copy[g] @ 512+g*16. No resets ever.

// ---------------- scan LDS (bytes) ----------------
// B operand: hi [256 kk][16 b] 16B blocks, row stride 272B; lo at +BLO_B.
// kk 0..127 = partner hE octets (x-part, odd only); kk 128..255 = own hR octets.
constexpr int BLO_B  = 69632;
constexpr int PART_F = 34816;      // float idx (byte 139264): [8 waves][16 r pad 17]
constexpr int SMEM_BYTES = 147968;

typedef __attribute__((ext_vector_type(8))) short bf16x8;
typedef __attribute__((ext_vector_type(4))) float f32x4;

__device__ __forceinline__ unsigned short f2bf(float f)
{
    union { float f; unsigned u; } v{f};
    unsigned r = v.u + 0x7FFFu + ((v.u >> 16) & 1u);   // RNE
    return (unsigned short)(r >> 16);
}
__device__ __forceinline__ float bf2f(unsigned short h)
{
    union { unsigned u; float f; } v{(unsigned)h << 16};
    return v.f;
}

// ---------------- split conversion: fp32 -> bf16 hi + bf16 lo ----------------
__global__ __launch_bounds__(256) void conv_split(const float* __restrict__ in,
                                                  ushort* __restrict__ oh,
                                                  ushort* __restrict__ ol, int n4)
{
    int g = blockIdx.x * blockDim.x + threadIdx.x;
    if (g >= n4) return;
    float4 f = ((const float4*)in)[g];
    ushort4 h, l;
    h.x = f2bf(f.x); l.x = f2bf(f.x - bf2f(h.x));
    h.y = f2bf(f.y); l.y = f2bf(f.y - bf2f(h.y));
    h.z = f2bf(f.z); l.z = f2bf(f.z - bf2f(h.z));
    h.w = f2bf(f.w); l.w = f2bf(f.w - bf2f(h.w));
    ((ushort4*)oh)[g] = h;
    ((ushort4*)ol)[g] = l;
}

// ---------------- MFMA GEMM (unchanged, verified) ----------------
__global__ __launch_bounds__(256) void gemm_mfma(const ushort* __restrict__ Ah,
                                                 const ushort* __restrict__ Al,
                                                 const ushort* __restrict__ Wh,
                                                 const ushort* __restrict__ Wl,
                                                 const float* __restrict__ bih,
                                                 const float* __restrict__ bhh,
                                                 float* __restrict__ out, int K)
{
    __shared__ ushort lds[2][128 * 72];
    const int tid = threadIdx.x;
    const int w = tid >> 6, ln = tid & 63;
    const int m0 = blockIdx.y * 128, n0 = blockIdx.x * 128;
    const int arow = (w >> 1) * 64, bcol = (w & 1) * 64;
    const int lm = ln & 15, lk = (ln >> 4) * 8;
    const int sr = tid >> 3, sc = (tid & 7) * 8;

    f32x4 acc[4][4] = {};

#pragma unroll
    for (int s = 0; s < 3; ++s) {
        const ushort* Asrc = (s < 2) ? Ah : Al;
        const ushort* Bsrc = (s == 1) ? Wl : Wh;
        for (int k0 = 0; k0 < K; k0 += 64) {
            __syncthreads();
#pragma unroll
            for (int i = 0; i < 4; ++i) {
                int r = sr + 32 * i;
                *(uint4*)&lds[0][r * 72 + sc] =
                    *(const uint4*)(Asrc + (size_t)(m0 + r) * K + k0 + sc);
                *(uint4*)&lds[1][r * 72 + sc] =
                    *(const uint4*)(Bsrc + (size_t)(n0 + r) * K + k0 + sc);
            }
            __syncthreads();
#pragma unroll
            for (int ks = 0; ks < 2; ++ks) {
                bf16x8 af[4], bf[4];
#pragma unroll
                for (int i = 0; i < 4; ++i)
                    af[i] = *(const bf16x8*)&lds[0][(arow + i * 16 + lm) * 72 + ks * 32 + lk];
#pragma unroll
                for (int j = 0; j < 4; ++j)
                    bf[j] = *(const bf16x8*)&lds[1][(bcol + j * 16 + lm) * 72 + ks * 32 + lk];
#pragma unroll
                for (int i = 0; i < 4; ++i)
#pragma unroll
                    for (int j = 0; j < 4; ++j)
                        acc[i][j] = __builtin_amdgcn_mfma_f32_16x16x32_bf16(
                            af[i], bf[j], acc[i][j], 0, 0, 0);
            }
        }
    }

#pragma unroll
    for (int j = 0; j < 4; ++j) {
        const int n = n0 + bcol + j * 16 + lm;
        const float bsum = bih[n] + bhh[n];
#pragma unroll
        for (int i = 0; i < 4; ++i) {
            const int mrow = m0 + arow + i * 16 + (ln >> 4) * 4;
#pragma unroll
            for (int r = 0; r < 4; ++r) {
                const int m = mrow + r;
                const int bb = m >> 8, tt = m & 255;
                out[(size_t)(tt * 16 + bb) * GG + n] = acc[i][j][r] + bsum;
            }
        }
    }
}

__device__ __forceinline__ float sigf(float x) { return 1.0f / (1.0f + expf(-x)); }

// ---------------- paired-layer LSTM scan: layers 2p (WGs 0-127) + 2p+1 (WGs 128-255) --
// Per half: WG lwg owns h-cols j0=8*lwg..+7 -> 32 gate rows r: gate=r>>3, col=j0+(r&7).
// Wave w: tile t_w=w&1 (rows t_w*16..+15), k-slice s_w=w>>1 (k in [256*s_w,+256)).
// Even: gate input = precomputed xg (fp32). Odd: gate input = bias; x-contribution
// W_ih @ h(2p,t) fused as MFMAs from partner's coherent parity buffer.
__global__ __launch_bounds__(512, 1) void scan_pair(
    const float* __restrict__ WhhE, const float* __restrict__ WhhO,
    const float* __restrict__ WihO, const float* __restrict__ xg,
    ushort* __restrict__ hseq_hi, ushort* __restrict__ hseq_lo,
    unsigned* __restrict__ hEbuf, unsigned* __restrict__ hObuf,
    const float* __restrict__ bihO, const float* __restrict__ bhhO,
    unsigned* __restrict__ barE, unsigned* __restrict__ barO,
    unsigned base)
{
    extern __shared__ float smem[];
    char* smb = (char*)smem;
    const int tid  = threadIdx.x;
    const int wgid = blockIdx.x;
    const int half = wgid >> 7, lwg = wgid & 127;
    const int j0 = lwg << 3;
    const int w = tid >> 6, ln = tid & 63;
    const int m = ln & 15, kq = ln >> 4;
    const int t_w = w & 1, s_w = w >> 1;
    const int grp = lwg >> 4;

    unsigned* myBar = half ? barO : barE;
    unsigned* otBar = half ? barE : barO;
    unsigned* myH   = half ? hObuf : hEbuf;   // own recurrence src + dst

    // ---- W_hh fragments (step-invariant)
    bf16x8 wf_hi[8], wf_lo[8];
    {
        const int r = t_w * 16 + m;
        const int grow = ((r >> 3) << 10) + j0 + (r & 7);
        const float* wrow = (half ? WhhO : WhhE) + (size_t)grow * 1024 + (s_w << 8) + (kq << 3);
#pragma unroll
        for (int s = 0; s < 8; ++s) {
            float4 f0 = *(const float4*)(wrow + s * 32);
            float4 f1 = *(const float4*)(wrow + s * 32 + 4);
            float fv[8] = {f0.x, f0.y, f0.z, f0.w, f1.x, f1.y, f1.z, f1.w};
            bf16x8 h8, l8;
#pragma unroll
            for (int i = 0; i < 8; ++i) {
                unsigned short hb = f2bf(fv[i]);
                h8[i] = (short)hb;
                l8[i] = (short)f2bf(fv[i] - bf2f(hb));
            }
            wf_hi[s] = h8; wf_lo[s] = l8;
        }
    }
    // ---- W_ih fragments (odd half only)
    bf16x8 uf_hi[8], uf_lo[8];
    if (half) {
        const int r = t_w * 16 + m;
        const int grow = ((r >> 3) << 10) + j0 + (r & 7);
        const float* wrow = WihO + (size_t)grow * 1024 + (s_w << 8) + (kq << 3);
#pragma unroll
        for (int s = 0; s < 8; ++s) {
            float4 f0 = *(const float4*)(wrow + s * 32);
            float4 f1 = *(const float4*)(wrow + s * 32 + 4);
            float fv[8] = {f0.x, f0.y, f0.z, f0.w, f1.x, f1.y, f1.z, f1.w};
            bf16x8 h8, l8;
#pragma unroll
            for (int i = 0; i < 8; ++i) {
                unsigned short hb = f2bf(fv[i]);
                h8[i] = (short)hb;
                l8[i] = (short)f2bf(fv[i] - bf2f(hb));
            }
            uf_hi[s] = h8; uf_lo[s] = l8;
        }
    }

    // staging lane mapping (round-11 proven)
    const int bidx = ln >> 4, jj = ln & 15;
    const int kkloc = jj >> 1, sub = (jj & 1) * 8;
    // gate lanes (tid<64)
    const int q = tid >> 4, bg = tid & 15;

    float cs0 = 0.f, cs1 = 0.f;
    float2 gin[4] = {};   // per-step gate input: xg (even) or bias (odd, constant)
    if (tid < 64) {
        if (half) {
#pragma unroll
            for (int g = 0; g < 4; ++g) {
                const int c0 = g * 1024 + j0 + 2 * q;
                gin[g] = make_float2(bihO[c0] + bhhO[c0], bihO[c0 + 1] + bhhO[c0 + 1]);
            }
        } else {
#pragma unroll
            for (int g = 0; g < 4; ++g)
                gin[g] = *(const float2*)(xg + (size_t)bg * GG + g * 1024 + j0 + 2 * q);
        }
    }

    for (int t = 0; t < TT; ++t) {
        const unsigned gt = base + (unsigned)t;
        // ---- 1. waits (tid0 only, relaxed, spread gen lines)
        if (tid == 0) {
            if (t > 0) {
                unsigned* p = myBar + 512 + (grp << 4);
                while (__hip_atomic_load(p, __ATOMIC_RELAXED, __HIP_MEMORY_SCOPE_AGENT) < gt)
                    __builtin_amdgcn_s_sleep(1);
            }
            if (half) {   // need partner h(2p, t)
                unsigned* p = otBar + 512 + (grp << 4);
                while (__hip_atomic_load(p, __ATOMIC_RELAXED, __HIP_MEMORY_SCOPE_AGENT) < gt + 1u)
                    __builtin_amdgcn_s_sleep(1);
            } else if (t >= 4) {   // back-pressure: don't overwrite slot odd still reads
                unsigned* p = otBar + 512 + (grp << 4);
                while (__hip_atomic_load(p, __ATOMIC_RELAXED, __HIP_MEMORY_SCOPE_AGENT) < gt - 3u)
                    __builtin_amdgcn_s_sleep(1);
            }
        }
        __syncthreads();

        // ---- 2. stage B operands (coalesced coherent loads -> LDS)
        uint4 vE[2][4], vR[2][4];
        if (half) {
            const uint4* pEb = (const uint4*)(hEbuf + ((unsigned)(t & 3) << 14));
#pragma unroll
            for (int cc = 0; cc < 2; ++cc) {
                const uint4* p = pEb + ((w << 1) + cc) * 256 + ln;
                asm volatile(
                    "global_load_dwordx4 %0, %4, off sc0 sc1\n\t"
                    "global_load_dwordx4 %1, %4, off offset:1024 sc0 sc1\n\t"
                    "global_load_dwordx4 %2, %4, off offset:2048 sc0 sc1\n\t"
                    "global_load_dwordx4 %3, %4, off offset:3072 sc0 sc1"
                    : "=&v"(vE[cc][0]), "=&v"(vE[cc][1]), "=&v"(vE[cc][2]), "=&v"(vE[cc][3])
                    : "v"(p) : "memory");
            }
        }
        if (t > 0) {
            const uint4* pRb = (const uint4*)(myH + ((unsigned)((t - 1) & 3) << 14));
#pragma unroll
            for (int cc = 0; cc < 2; ++cc) {
                const uint4* p = pRb + ((w << 1) + cc) * 256 + ln;
                asm volatile(
                    "global_load_dwordx4 %0, %4, off sc0 sc1\n\t"
                    "global_load_dwordx4 %1, %4, off offset:1024 sc0 sc1\n\t"
                    "global_load_dwordx4 %2, %4, off offset:2048 sc0 sc1\n\t"
                    "global_load_dwordx4 %3, %4, off offset:3072 sc0 sc1"
                    : "=&v"(vR[cc][0]), "=&v"(vR[cc][1]), "=&v"(vR[cc][2]), "=&v"(vR[cc][3])
                    : "v"(p) : "memory");
            }
        }
        if (half || t > 0) {
            asm volatile("s_waitcnt vmcnt(0)" ::: "memory");
            __builtin_amdgcn_sched_barrier(0);
        }
        if (half) {
#pragma unroll
            for (int cc = 0; cc < 2; ++cc) {
                const int kk = ((w << 1) + cc) * 8 + kkloc;          // 0..127
#pragma unroll
                for (int i = 0; i < 4; ++i) {
                    const int b = (i << 2) + bidx;
                    uint4 pv = vE[cc][i];
                    uint2 uh = {(pv.x & 0xFFFFu) | (pv.y << 16),
                                (pv.z & 0xFFFFu) | (pv.w << 16)};
                    uint2 ul = {(pv.x >> 16) | (pv.y & 0xFFFF0000u),
                                (pv.z >> 16) | (pv.w & 0xFFFF0000u)};
                    char* bp = smb + kk * 272 + b * 16 + sub;
                    *(uint2*)bp = uh;
                    *(uint2*)(bp + BLO_B) = ul;
                }
            }
        }
        if (t > 0) {
#pragma unroll
            for (int cc = 0; cc < 2; ++cc) {
                const int kk = 128 + ((w << 1) + cc) * 8 + kkloc;    // 128..255
#pragma unroll
                for (int i = 0; i < 4; ++i) {
                    const int b = (i << 2) + bidx;
                    uint4 pv = vR[cc][i];
                    uint2 uh = {(pv.x & 0xFFFFu) | (pv.y << 16),
                                (pv.z & 0xFFFFu) | (pv.w << 16)};
                    uint2 ul = {(pv.x >> 16) | (pv.y & 0xFFFF0000u),
                                (pv.z >> 16) | (pv.w & 0xFFFF0000u)};
                    char* bp = smb + kk * 272 + b * 16 + sub;
                    *(uint2*)bp = uh;
                    *(uint2*)(bp + BLO_B) = ul;
                }
            }
        }
        __syncthreads();

        // ---- 3. MFMAs: odd x-part (8 ksteps) + recurrence (8 ksteps), 3 chains
        f32x4 aA = {0.f, 0.f, 0.f, 0.f};
        f32x4 aB = {0.f, 0.f, 0.f, 0.f};
        f32x4 aC = {0.f, 0.f, 0.f, 0.f};
        const char* hbx = smb + ((s_w << 5) + kq) * 272 + m * 16;
        const char* hbr = hbx + 128 * 272;
        if (half) {
#pragma unroll
            for (int s = 0; s < 8; ++s) {
                bf16x8 bh = *(const bf16x8*)(hbx + s * 1088);
                bf16x8 bl = *(const bf16x8*)(hbx + BLO_B + s * 1088);
                aA = __builtin_amdgcn_mfma_f32_16x16x32_bf16(uf_hi[s], bh, aA, 0, 0, 0);
                aB = __builtin_amdgcn_mfma_f32_16x16x32_bf16(uf_hi[s], bl, aB, 0, 0, 0);
                aC = __builtin_amdgcn_mfma_f32_16x16x32_bf16(uf_lo[s], bh, aC, 0, 0, 0);
            }
        }
        if (t > 0) {
#pragma unroll
            for (int s = 0; s < 8; ++s) {
                bf16x8 bh = *(const bf16x8*)(hbr + s * 1088);
                bf16x8 bl = *(const bf16x8*)(hbr + BLO_B + s * 1088);
                aA = __builtin_amdgcn_mfma_f32_16x16x32_bf16(wf_hi[s], bh, aA, 0, 0, 0);
                aB = __builtin_amdgcn_mfma_f32_16x16x32_bf16(wf_hi[s], bl, aB, 0, 0, 0);
                aC = __builtin_amdgcn_mfma_f32_16x16x32_bf16(wf_lo[s], bh, aC, 0, 0, 0);
            }
        }
        f32x4 asum = aA + aB;
        asum = asum + aC;

        // ---- 4. partials: [wave][row=kq*4+r pad17][b=m]
#pragma unroll
        for (int r = 0; r < 4; ++r)
            smem[PART_F + w * 272 + ((kq << 2) + r) * 17 + m] = asum[r];
        __syncthreads();

        // ---- 5. gates (wave 0): reduce 8 wave-partials + gin, activations, h store
        unsigned pk0 = 0, pk1 = 0;
        if (tid < 64) {
#pragma unroll
            for (int cc = 0; cc < 2; ++cc) {
                const int ch = 2 * q + cc;
                float iv = cc ? gin[0].y : gin[0].x;
                float fv = cc ? gin[1].y : gin[1].x;
                float gv = cc ? gin[2].y : gin[2].x;
                float ov = cc ? gin[3].y : gin[3].x;
#pragma unroll
                for (int s = 0; s < 4; ++s) {
                    iv += smem[PART_F + (2 * s    ) * 272 + (ch    ) * 17 + bg];
                    fv += smem[PART_F + (2 * s    ) * 272 + (ch + 8) * 17 + bg];
                    gv += smem[PART_F + (2 * s + 1) * 272 + (ch    ) * 17 + bg];
                    ov += smem[PART_F + (2 * s + 1) * 272 + (ch + 8) * 17 + bg];
                }
                float& cs = cc ? cs1 : cs0;
                cs = sigf(fv) * cs + sigf(iv) * tanhf(gv);
                float hval = sigf(ov) * tanhf(cs);
                unsigned short hh_ = f2bf(hval);
                unsigned short hl_ = f2bf(hval - bf2f(hh_));
                unsigned pk = (unsigned)hh_ | ((unsigned)hl_ << 16);
                if (cc) pk1 = pk; else pk0 = pk;
                const int col = j0 + ch;
                unsigned* hdst = myH + ((unsigned)(t & 3) << 14) +
                                 ((col >> 6) << 10) + (bg << 6) + (col & 63);
                asm volatile("global_store_dword %0, %1, off sc0 sc1"
                             :: "v"(hdst), "v"(pk) : "memory");
            }
        }

        // ---- 6. arrive (monotonic tree, no resets)
        if (tid == 0) {
            asm volatile("s_waitcnt vmcnt(0)" ::: "memory");   // wave-0 h stores acked
            const unsigned T = gt + 1u;
            unsigned a = __hip_atomic_fetch_add(myBar + (grp << 4), 1u,
                                                __ATOMIC_RELAXED, __HIP_MEMORY_SCOPE_AGENT);
            if (a == 16u * T - 1u) {
                unsigned ra = __hip_atomic_fetch_add(myBar + 256, 1u,
                                                     __ATOMIC_RELAXED, __HIP_MEMORY_SCOPE_AGENT);
                if (ra == 8u * T - 1u) {
#pragma unroll
                    for (int i = 0; i < 8; ++i)
                        __hip_atomic_store(myBar + 512 + (i << 4), T,
                                           __ATOMIC_RELAXED, __HIP_MEMORY_SCOPE_AGENT);
                }
            }
        }

        // ---- 7. off critical path: odd hseq; even xg prefetch
        if (tid < 64) {
            if (half) {
#pragma unroll
                for (int cc = 0; cc < 2; ++cc) {
                    const int col = j0 + 2 * q + cc;
                    const unsigned pk = cc ? pk1 : pk0;
                    size_t idx = (size_t)(bg * TT + t) * HH + col;
                    hseq_hi[idx] = (ushort)(pk & 0xFFFFu);
                    hseq_lo[idx] = (ushort)(pk >> 16);
                }
            } else if (t + 1 < TT) {
#pragma unroll
                for (int g = 0; g < 4; ++g)
                    gin[g] = *(const float2*)(xg + (size_t)((t + 1) * 16 + bg) * GG +
                                              g * 1024 + j0 + 2 * q);
            }
        }
    }
}

// ---------------- FC head ----------------
__global__ void fc_relu_split(const ushort* __restrict__ ih, const ushort* __restrict__ il,
                              const float* __restrict__ w, const float* __restrict__ b,
                              float* __restrict__ out, int N, int K)
{
    int g = blockIdx.x * blockDim.x + threadIdx.x;
    if (g >= BB * N) return;
    int bi = g / N, n = g - bi * N;
    const ushort* ph = ih + (size_t)(bi * 256 + 255) * 1024;
    const ushort* pl = il + (size_t)(bi * 256 + 255) * 1024;
    const float* wp = w + (size_t)n * K;
    float s = 0.f;
    for (int k = 0; k < K; k += 4) {
        ushort4 uh = *(const ushort4*)(ph + k);
        ushort4 ul = *(const ushort4*)(pl + k);
        float4 qv = *(const float4*)(wp + k);
        s += (bf2f(uh.x) + bf2f(ul.x)) * qv.x + (bf2f(uh.y) + bf2f(ul.y)) * qv.y +
             (bf2f(uh.z) + bf2f(ul.z)) * qv.z + (bf2f(uh.w) + bf2f(ul.w)) * qv.w;
    }
    s += b[n];
    out[g] = fmaxf(s, 0.f);
}

__global__ void fc_relu(const float* __restrict__ in, const float* __restrict__ w,
                        const float* __restrict__ b, float* __restrict__ out,
                        int N, int K, int do_relu)
{
    int g = blockIdx.x * blockDim.x + threadIdx.x;
    if (g >= BB * N) return;
    int bi = g / N, n = g - bi * N;
    const float* ip = in + (size_t)bi * K;
    const float* wp = w + (size_t)n * K;
    float s = 0.f;
    for (int k = 0; k < K; k += 4) {
        float4 a = *(const float4*)(ip + k);
        float4 qv = *(const float4*)(wp + k);
        s += a.x * qv.x + a.y * qv.y + a.z * qv.z + a.w * qv.w;
    }
    s += b[n];
    if (do_relu) s = fmaxf(s, 0.f);
    out[g] = s;
}

// ---------------- launch ----------------
extern "C" void kernel_launch(void* const* d_in, const int* in_sizes, int n_in,
                              void* d_out, int out_size, void* d_ws, size_t ws_size,
                              hipStream_t stream)
{
    const float* x    = (const float*)d_in[0];
    const float* Wih0 = (const float*)d_in[1];
    const float* WihR = (const float*)d_in[2];
    const float* Whh  = (const float*)d_in[3];
    const float* bih  = (const float*)d_in[4];
    const float* bhh  = (const float*)d_in[5];
    const float* fc1w = (const float*)d_in[6];
    const float* fc1b = (const float*)d_in[7];
    const float* fc2w = (const float*)d_in[8];
    const float* fc2b = (const float*)d_in[9];
    const float* fc3w = (const float*)d_in[10];
    const float* fc3b = (const float*)d_in[11];
    float* out = (float*)d_out;
    char* ws = (char*)d_ws;

    float* xg      = (float*)(ws + XG_OFF);
    ushort* reg0   = (ushort*)(ws + REG0_OFF);
    ushort* hs_hi  = (ushort*)(ws + REG1_OFF);
    ushort* hs_lo  = hs_hi + 4194304;
    unsigned* hE   = (unsigned*)(ws + HE_OFF);
    unsigned* hO   = (unsigned*)(ws + HO_OFF);
    float* fc1o    = (float*)(ws + FC1_OFF);
    float* fc2o    = (float*)(ws + FC2_OFF);
    unsigned* barE = (unsigned*)(ws + BAR_OFF);
    unsigned* barO = (unsigned*)(ws + BAR_OFF + 4096);

    (void)hipFuncSetAttribute((const void*)scan_pair,
                              hipFuncAttributeMaxDynamicSharedMemorySize, SMEM_BYTES);
    (void)hipMemsetAsync(ws + BAR_OFF, 0, 8192, stream);   // both bars = 0 (monotonic)

    // phase-0 conversions: xcv (8MB) + W_ih(0) split (8MB) into REG0
    ushort* xcv_hi = reg0;
    ushort* xcv_lo = reg0 + 2097152;
    ushort* w0h    = reg0 + 4194304;
    ushort* w0l    = reg0 + 6291456;
    conv_split<<<2048, 256, 0, stream>>>(x, xcv_hi, xcv_lo, (BB * TT * IN0) / 4);
    conv_split<<<2048, 256, 0, stream>>>(Wih0, w0h, w0l, (GG * IN0) / 4);
    gemm_mfma<<<dim3(32, 32), 256, 0, stream>>>(xcv_hi, xcv_lo, w0h, w0l,
                                                bih, bhh, xg, IN0);

    for (int p = 0; p < 4; ++p) {
        if (p > 0) {
            // xg(2p) = hseq(2p-1) @ W_ih(2p)^T + bias
            const float* Wl = WihR + (size_t)(2 * p - 1) * GG * HH;
            conv_split<<<4096, 256, 0, stream>>>(Wl, reg0, reg0 + 4194304, (GG * HH) / 4);
            gemm_mfma<<<dim3(32, 32), 256, 0, stream>>>(
                hs_hi, hs_lo, reg0, reg0 + 4194304,
                bih + (size_t)(2 * p) * GG, bhh + (size_t)(2 * p) * GG, xg, HH);
        }
        const float* whhE = Whh + (size_t)(2 * p) * GG * HH;
        const float* whhO = Whh + (size_t)(2 * p + 1) * GG * HH;
        const float* wihO = WihR + (size_t)(2 * p) * GG * HH;      // W_ih(2p+1)
        const float* bO   = bih + (size_t)(2 * p + 1) * GG;
        const float* bhO  = bhh + (size_t)(2 * p + 1) * GG;
        unsigned base = 256u * (unsigned)p;
        void* args[13] = {(void*)&whhE, (void*)&whhO, (void*)&wihO, (void*)&xg,
                          (void*)&hs_hi, (void*)&hs_lo, (void*)&hE, (void*)&hO,
                          (void*)&bO, (void*)&bhO, (void*)&barE, (void*)&barO,
                          (void*)&base};
        hipError_t e = hipLaunchCooperativeKernel((void*)scan_pair, dim3(256), dim3(512),
                                                  args, SMEM_BYTES, stream);
        if (e != hipSuccess) {
            scan_pair<<<dim3(256), dim3(512), SMEM_BYTES, stream>>>(
                whhE, whhO, wihO, xg, hs_hi, hs_lo, hE, hO, bO, bhO, barE, barO, base);
        }
    }

    // FC head: hseq(7) in REG1
    fc_relu_split<<<32, 256, 0, stream>>>(hs_hi, hs_lo, fc1w, fc1b, fc1o, 512, 1024);
    fc_relu<<<16, 256, 0, stream>>>(fc1o, fc2w, fc2b, fc2o, 256, 512, 1);
    fc_relu<<<1, 16, 0, stream>>>(fc2o, fc3w, fc3b, out, 1, 256, 0);
}